// Round 8
// baseline (100.674 us; speedup 1.0000x reference)
//
#include <hip/hip_runtime.h>

#define EMBED 2048
#define HEAD 128
#define BATCH 8
#define SEQ 2048

typedef __attribute__((ext_vector_type(4))) float f32x4;
typedef __attribute__((ext_vector_type(8))) __bf16 bf16x8;
typedef __attribute__((ext_vector_type(8))) short short8;

static __device__ __forceinline__ ushort f2bf(float x){
    unsigned u = __float_as_uint(x);
    u += 0x7fffu + ((u >> 16) & 1u);
    return (ushort)(u >> 16);
}

#define MFMA16(a,b,c) __builtin_amdgcn_mfma_f32_16x16x32_bf16((a),(b),(c),0,0,0)

#define GLL16(g, l) __builtin_amdgcn_global_load_lds( \
    (const __attribute__((address_space(1))) void*)(g), \
    (__attribute__((address_space(3))) void*)(l), 16, 0, 0)

// ---------------- prep: W [2048][128] f32 -> W^T [3*128][2048] bf16 (LDS transpose) ----------------
__global__ __launch_bounds__(256) void prep_wt(const float* __restrict__ Wq,
                                               const float* __restrict__ Wk,
                                               const float* __restrict__ Wv,
                                               ushort* __restrict__ wt){
    __shared__ float ld[64][129];
    const int w  = blockIdx.y;
    const int k0 = blockIdx.x * 64;
    const int tid = threadIdx.x;
    const float* W = (w == 0) ? Wq : ((w == 1) ? Wk : Wv);
    #pragma unroll
    for (int ii = 0; ii < 32; ii++){
        int idx = tid + 256 * ii;
        int row = idx >> 7, col = idx & 127;
        ld[row][col] = W[(size_t)(k0 + row) * HEAD + col];
    }
    __syncthreads();
    int n  = tid >> 1;
    int kh = (tid & 1) * 32;
    __attribute__((aligned(16))) ushort tmp[32];
    #pragma unroll
    for (int ii = 0; ii < 32; ii++) tmp[ii] = f2bf(ld[kh + ii][n]);
    ushort* dst = wt + (size_t)(w * HEAD + n) * EMBED + k0 + kh;
    #pragma unroll
    for (int q = 0; q < 4; q++)
        *(short8*)(dst + q * 8) = *(const short8*)(tmp + q * 8);
}

// ---------------- Fused QKV GEMM: [16384 x 2048] x [2048 x 384], x read ONCE ----------------
// BM=32, BN=384, BK=64, 256 thr (4 waves; wave tile 32 x 96). Grid 512 = 2 blocks/CU.
// LDS 53.8KB single-buffered (x 4.6KB + W 48KB) -> 2 resident blocks overlap each other's stalls.
// Per iter: ds_write x(kt) | GLL W(kt) | load x(kt+1) | lgkm0 + vmcnt(2) + bar | MFMA | bar.
__global__ __launch_bounds__(256, 2) void qkv_gemm(const float* __restrict__ x,
                                                   const ushort* __restrict__ wt,
                                                   const float* __restrict__ bq,
                                                   const float* __restrict__ bk,
                                                   const float* __restrict__ bv,
                                                   ushort* __restrict__ Qb,
                                                   ushort* __restrict__ Kb,
                                                   ushort* __restrict__ Vt){
    __shared__ char smem[53760];
    // xs = smem            [32][144B] padded bf16
    // wl = smem + 4608     [384][128B] linear, chunk-swizzled
    float* ts = (float*)smem;   // epilogue V transpose overlay [32][132] f32

    const int mtile = blockIdx.x;           // 0..511 (32 rows each)
    const int tid   = threadIdx.x;
    const int lane  = tid & 63;
    const int wid   = tid >> 6;             // 0..3 (n-split)
    const int l15   = lane & 15, lhi = lane >> 4;
    const int wn    = wid;
    const int xrow0 = mtile * 32;

    const int srow = tid >> 3;              // 0..31 x stage row
    const int ssub = tid & 7;               // 8-f32 chunk

    const int grow = lane >> 3;             // gll: row within 8-row group (=row&7)
    const int gch  = lane & 7;              // gll: 16B chunk

    char* xs = smem;
    char* wl = smem + 4608;

    f32x4 acc[2][6];
    #pragma unroll
    for (int i = 0; i < 2; i++)
        #pragma unroll
        for (int j = 0; j < 6; j++) acc[i][j] = (f32x4){0.f,0.f,0.f,0.f};

    const int NK = EMBED / 64;
    float4 xr0, xr1;
    {   // prologue: x(0) into regs
        const float* xp = x + (size_t)(xrow0 + srow) * EMBED;
        xr0 = *(const float4*)(xp + ssub * 8);
        xr1 = *(const float4*)(xp + ssub * 8 + 4);
    }

    for (int kt = 0; kt < NK; ++kt){
        // 1) x(kt) regs -> LDS (auto-waits just those 2 loads)
        {
            __attribute__((aligned(16))) ushort t8[8];
            t8[0]=f2bf(xr0.x); t8[1]=f2bf(xr0.y); t8[2]=f2bf(xr0.z); t8[3]=f2bf(xr0.w);
            t8[4]=f2bf(xr1.x); t8[5]=f2bf(xr1.y); t8[6]=f2bf(xr1.z); t8[7]=f2bf(xr1.w);
            *(short8*)(xs + srow * 144 + ssub * 16) = *(const short8*)t8;
        }
        // 2) GLL W(kt): 96 rows/wave, 12 x 1KB
        {
            const ushort* wsrc = wt + kt * 64;
            #pragma unroll
            for (int g = 0; g < 12; g++){
                int r0  = wid * 96 + g * 8;
                int row = r0 + grow;
                GLL16(wsrc + (size_t)row * EMBED + ((gch ^ grow) * 8), wl + r0 * 128);
            }
        }
        // 3) x(kt+1) into regs (newest vmem -> excluded from vmcnt(2) wait)
        if (kt < NK - 1){
            const float* xp = x + (size_t)(xrow0 + srow) * EMBED + (kt + 1) * 64;
            xr0 = *(const float4*)(xp + ssub * 8);
            xr1 = *(const float4*)(xp + ssub * 8 + 4);
        }
        // 4) make x ds_writes + W GLLs visible; keep x(kt+1) in flight
        asm volatile("s_waitcnt lgkmcnt(0)" ::: "memory");
        if (kt < NK - 1) asm volatile("s_waitcnt vmcnt(2)" ::: "memory");
        else             asm volatile("s_waitcnt vmcnt(0)" ::: "memory");
        __builtin_amdgcn_s_barrier();

        // 5) compute
        #pragma unroll
        for (int kc = 0; kc < 2; kc++){
            bf16x8 af[2], bfj[6];
            #pragma unroll
            for (int i = 0; i < 2; i++)
                af[i] = *(const bf16x8*)(xs + (i*16 + l15) * 144 + kc*64 + lhi*16);
            #pragma unroll
            for (int j = 0; j < 6; j++){
                int row = wn*96 + j*16 + l15;
                bfj[j] = *(const bf16x8*)(wl + row * 128 + (((kc*4 + lhi) ^ (l15 & 7)) * 16));
            }
            #pragma unroll
            for (int i = 0; i < 2; i++)
                #pragma unroll
                for (int j = 0; j < 6; j++)
                    acc[i][j] = MFMA16(af[i], bfj[j], acc[i][j]);
        }
        // 6) all readers done before next iter overwrites x/W
        __builtin_amdgcn_s_barrier();
    }

    // ---- epilogue ----
    float bval[6];
    #pragma unroll
    for (int j = 0; j < 6; j++){
        int c = wn*96 + j*16 + l15;
        bval[j] = (c < 128) ? bq[c] : ((c < 256) ? bk[c - 128] : bv[c - 256]);
    }
    #pragma unroll
    for (int j = 0; j < 6; j++){
        int cb = wn*96 + j*16;          // 16-aligned; wholly within Q, K, or V
        if (cb < 256){
            ushort* dst = (cb < 128) ? Qb : Kb;
            int cl = (cb & 127) + l15;
            #pragma unroll
            for (int i = 0; i < 2; i++)
                #pragma unroll
                for (int r = 0; r < 4; r++){
                    int m = mtile*32 + i*16 + lhi*4 + r;
                    dst[(size_t)m * HEAD + cl] = f2bf(acc[i][j][r] + bval[j]);
                }
        }
    }
    __syncthreads();   // done with xs/wl; reuse as ts
    #pragma unroll
    for (int j = 0; j < 6; j++){
        int cb = wn*96 + j*16;
        if (cb >= 256){
            int vc = cb - 256 + l15;
            #pragma unroll
            for (int i = 0; i < 2; i++)
                #pragma unroll
                for (int r = 0; r < 4; r++){
                    int ml = i*16 + lhi*4 + r;
                    ts[ml * 132 + vc] = acc[i][j][r] + bval[j];
                }
        }
    }
    __syncthreads();
    {   // transpose out: V [32 rows][128 cols] -> Vt [8][128][2048]
        int n  = tid >> 1;              // 0..127 col
        int mc = (tid & 1) * 16;        // row group
        int bb = mtile >> 6;            // 64 mtiles per batch
        int trow = (mtile & 63) * 32 + mc;
        __attribute__((aligned(16))) ushort tmp[16];
        #pragma unroll
        for (int ii = 0; ii < 16; ii++) tmp[ii] = f2bf(ts[(mc + ii) * 132 + n]);
        ushort* dst = Vt + ((size_t)(bb * HEAD + n)) * SEQ + trow;
        *(short8*)(dst)     = *(const short8*)(tmp);
        *(short8*)(dst + 8) = *(const short8*)(tmp + 8);
    }
}

// ---------------- Flash attention, causal, kv-split x2, async-staged ----------------
__global__ __launch_bounds__(256) void attn(const ushort* __restrict__ Qb,
                                            const ushort* __restrict__ Kb,
                                            const ushort* __restrict__ Vt,
                                            float* __restrict__ po,
                                            float* __restrict__ pm,
                                            float* __restrict__ pl){
    __shared__ char smem[40960];
    char* Ks = smem;            // [64 kv][256 B] chunk-swizzled (^row&15)
    char* Vs = smem + 16384;    // [128 d][128 B] chunk-swizzled (^d&7)
    char* Ps = smem + 32768;    // 4 waves x [16 q][128 B] chunk-swizzled (^q&7)

    const int slot = blockIdx.x;
    const int b    = blockIdx.y;
    const int qi   = slot >> 1;
    const int qt   = (b < 4) ? qi : (31 - qi);     // anti-correlated pairing
    const int half = slot & 1;
    const int NT   = qt + 1;
    const int tmid = (NT + 1) >> 1;
    const int t0   = half ? tmid : 0;
    const int t1   = half ? NT : tmid;

    const int qb    = qt * 64;
    const int tid   = threadIdx.x;
    const int lane  = tid & 63, wid = tid >> 6;
    const int l15   = lane & 15, lhi = lane >> 4;
    const float scale = 0.08838834764831845f;   // 1/sqrt(128)

    bf16x8 qf[4];
    {
        const ushort* qp = Qb + ((size_t)(b * SEQ + qb + wid * 16 + l15)) * HEAD;
        #pragma unroll
        for (int kc = 0; kc < 4; kc++)
            qf[kc] = *(const bf16x8*)(qp + kc * 32 + lhi * 8);
    }

    f32x4 o[8];
    #pragma unroll
    for (int d = 0; d < 8; d++) o[d] = (f32x4){0.f,0.f,0.f,0.f};
    float mr[4] = {-1e30f,-1e30f,-1e30f,-1e30f};
    float lr[4] = {0.f,0.f,0.f,0.f};

    char* Pw = Ps + wid * 2048;

    const int krow = tid >> 4, kch = tid & 15;   // K stage coords
    const int vd   = tid >> 3, vch = tid & 7;    // V stage coords

    short8 kr[4], vr[4];
    {
        const int kvb = t0 * 64;
        #pragma unroll
        for (int j = 0; j < 4; j++)
            kr[j] = *(const short8*)(Kb + ((size_t)(b * SEQ + kvb + krow + 16*j)) * HEAD + kch * 8);
        #pragma unroll
        for (int j = 0; j < 4; j++)
            vr[j] = *(const short8*)(Vt + ((size_t)(b * HEAD + vd + 32*j)) * SEQ + kvb + vch * 8);
    }

    for (int t = t0; t < t1; ++t){
        __syncthreads();
        #pragma unroll
        for (int j = 0; j < 4; j++){
            int row = krow + 16*j;
            *(short8*)(Ks + row * 256 + ((kch ^ (row & 15)) * 16)) = kr[j];
        }
        #pragma unroll
        for (int j = 0; j < 4; j++){
            int d = vd + 32*j;
            *(short8*)(Vs + d * 128 + ((vch ^ (d & 7)) * 16)) = vr[j];
        }
        if (t + 1 < t1){
            const int kvb2 = (t + 1) * 64;
            #pragma unroll
            for (int j = 0; j < 4; j++)
                kr[j] = *(const short8*)(Kb + ((size_t)(b * SEQ + kvb2 + krow + 16*j)) * HEAD + kch * 8);
            #pragma unroll
            for (int j = 0; j < 4; j++)
                vr[j] = *(const short8*)(Vt + ((size_t)(b * HEAD + vd + 32*j)) * SEQ + kvb2 + vch * 8);
        }
        asm volatile("s_waitcnt lgkmcnt(0)" ::: "memory");
        __builtin_amdgcn_s_barrier();
        __builtin_amdgcn_sched_barrier(0);

        const int kvb = t * 64;
        f32x4 s[4];
        #pragma unroll
        for (int ns = 0; ns < 4; ns++){
            s[ns] = (f32x4){0.f,0.f,0.f,0.f};
            int row = ns * 16 + l15;
            #pragma unroll
            for (int kc = 0; kc < 4; kc++){
                int ch = (kc * 4 + lhi) ^ (row & 15);
                bf16x8 bfr = *(const bf16x8*)(Ks + row * 256 + ch * 16);
                s[ns] = MFMA16(qf[kc], bfr, s[ns]);
            }
        }

        float mx[4];
        #pragma unroll
        for (int r = 0; r < 4; r++){
            #pragma unroll
            for (int ns = 0; ns < 4; ns++){
                float v = s[ns][r] * scale;
                if (t == qt){
                    int kvg = kvb + ns * 16 + l15;
                    int qg  = qb + wid * 16 + lhi * 4 + r;
                    if (kvg > qg) v = -1e30f;
                }
                s[ns][r] = v;
            }
            float m0 = fmaxf(fmaxf(s[0][r], s[1][r]), fmaxf(s[2][r], s[3][r]));
            m0 = fmaxf(m0, __shfl_xor(m0, 1));
            m0 = fmaxf(m0, __shfl_xor(m0, 2));
            m0 = fmaxf(m0, __shfl_xor(m0, 4));
            m0 = fmaxf(m0, __shfl_xor(m0, 8));
            mx[r] = m0;
        }
        float alpha[4];
        #pragma unroll
        for (int r = 0; r < 4; r++){
            float mn = fmaxf(mr[r], mx[r]);
            alpha[r] = __expf(mr[r] - mn);
            mr[r] = mn;
            float sum = 0.f;
            #pragma unroll
            for (int ns = 0; ns < 4; ns++){
                float p = __expf(s[ns][r] - mn);
                s[ns][r] = p;
                sum += p;
            }
            sum += __shfl_xor(sum, 1);
            sum += __shfl_xor(sum, 2);
            sum += __shfl_xor(sum, 4);
            sum += __shfl_xor(sum, 8);
            lr[r] = lr[r] * alpha[r] + sum;
        }
        #pragma unroll
        for (int d = 0; d < 8; d++)
            #pragma unroll
            for (int r = 0; r < 4; r++) o[d][r] *= alpha[r];

        #pragma unroll
        for (int ns = 0; ns < 4; ns++)
            #pragma unroll
            for (int r = 0; r < 4; r++){
                int row = lhi * 4 + r;
                int byteoff = row * 128 + (((ns * 16 + l15) * 2) ^ ((row & 7) << 4));
                *(ushort*)(Pw + byteoff) = f2bf(s[ns][r]);
            }
        asm volatile("s_waitcnt lgkmcnt(0)" ::: "memory");
        __builtin_amdgcn_sched_barrier(0);

        #pragma unroll
        for (int kc = 0; kc < 2; kc++){
            int abyte = l15 * 128 + ((kc * 64 + lhi * 16) ^ ((l15 & 7) << 4));
            bf16x8 af = *(const bf16x8*)(Pw + abyte);
            #pragma unroll
            for (int ds = 0; ds < 8; ds++){
                int drow = ds * 16 + l15;
                int bbyte = drow * 128 + ((kc * 64 + lhi * 16) ^ ((drow & 7) << 4));
                bf16x8 bfr = *(const bf16x8*)(Vs + bbyte);
                o[ds] = MFMA16(af, bfr, o[ds]);
            }
        }
    }

    float* pob = po + ((size_t)half * 16384 + (size_t)b * SEQ) * HEAD;
    #pragma unroll
    for (int r = 0; r < 4; r++){
        int q = qb + wid * 16 + lhi * 4 + r;
        #pragma unroll
        for (int ds = 0; ds < 8; ds++)
            pob[(size_t)q * HEAD + ds * 16 + l15] = o[ds][r];
        if (l15 == 0){
            pm[half * 16384 + b * SEQ + q] = mr[r];
            pl[half * 16384 + b * SEQ + q] = lr[r];
        }
    }
}

// ---------------- merge two kv-halves ----------------
__global__ __launch_bounds__(256) void merge(const float* __restrict__ po,
                                             const float* __restrict__ pm,
                                             const float* __restrict__ pl,
                                             float* __restrict__ out){
    int g = blockIdx.x * 256 + threadIdx.x;
    int row = g >> 2;
    int dq  = (g & 3) * 32;
    float m0 = pm[row], m1 = pm[16384 + row];
    float l0 = pl[row], l1 = pl[16384 + row];
    float M  = fmaxf(m0, m1);
    float w0 = __expf(m0 - M), w1 = __expf(m1 - M);
    float inv = 1.0f / (w0 * l0 + w1 * l1);
    const float4* p0 = (const float4*)(po + (size_t)row * HEAD + dq);
    const float4* p1 = (const float4*)(po + (size_t)(16384 + row) * HEAD + dq);
    float4* op = (float4*)(out + (size_t)row * HEAD + dq);
    #pragma unroll
    for (int i = 0; i < 8; i++){
        float4 a = p0[i], c = p1[i];
        float4 r;
        r.x = (w0*a.x + w1*c.x) * inv;
        r.y = (w0*a.y + w1*c.y) * inv;
        r.z = (w0*a.z + w1*c.z) * inv;
        r.w = (w0*a.w + w1*c.w) * inv;
        op[i] = r;
    }
}

extern "C" void kernel_launch(void* const* d_in, const int* in_sizes, int n_in,
                              void* d_out, int out_size, void* d_ws, size_t ws_size,
                              hipStream_t stream){
    const float* x  = (const float*)d_in[0];
    const float* Wq = (const float*)d_in[1];
    const float* bq = (const float*)d_in[2];
    const float* Wk = (const float*)d_in[3];
    const float* bk = (const float*)d_in[4];
    const float* Wv = (const float*)d_in[5];
    const float* bv = (const float*)d_in[6];
    float* out = (float*)d_out;

    char* ws = (char*)d_ws;
    ushort* Qb = (ushort*)ws;                                  // 4 MB   [16384][128]
    ushort* Kb = (ushort*)(ws + (size_t)4  * 1024 * 1024);     // 4 MB   [16384][128]
    ushort* Vt = (ushort*)(ws + (size_t)8  * 1024 * 1024);     // 4 MB   [8][128][2048]
    ushort* Wt = (ushort*)(ws + (size_t)12 * 1024 * 1024);     // 1.57MB [384][2048]
    float*  po = (float*) (ws + (size_t)14 * 1024 * 1024);     // 16.8MB [2][16384][128]
    float*  pm = (float*) (ws + (size_t)31 * 1024 * 1024);     // 131KB  [2][16384]
    float*  pl = (float*) (ws + (size_t)31 * 1024 * 1024 + 262144);

    prep_wt <<<dim3(32, 3), 256, 0, stream>>>(Wq, Wk, Wv, Wt);
    qkv_gemm<<<dim3(512), 256, 0, stream>>>(x, Wt, bq, bk, bv, Qb, Kb, Vt);
    attn    <<<dim3(64, 8), 256, 0, stream>>>(Qb, Kb, Vt, po, pm, pl);
    merge   <<<256, 256, 0, stream>>>(po, pm, pl, out);
}

// Round 9
// 98.018 us; speedup vs baseline: 1.0271x; 1.0271x over previous
//
#include <hip/hip_runtime.h>

#define EMBED 2048
#define HEAD 128
#define BATCH 8
#define SEQ 2048

typedef __attribute__((ext_vector_type(4))) float f32x4;
typedef __attribute__((ext_vector_type(8))) __bf16 bf16x8;
typedef __attribute__((ext_vector_type(8))) short short8;

static __device__ __forceinline__ ushort f2bf(float x){
    unsigned u = __float_as_uint(x);
    u += 0x7fffu + ((u >> 16) & 1u);
    return (ushort)(u >> 16);
}

#define MFMA16(a,b,c) __builtin_amdgcn_mfma_f32_16x16x32_bf16((a),(b),(c),0,0,0)

#define GLL16(g, l) __builtin_amdgcn_global_load_lds( \
    (const __attribute__((address_space(1))) void*)(g), \
    (__attribute__((address_space(3))) void*)(l), 16, 0, 0)

// ---------------- prep: W [2048][128] f32 -> W^T [3*128][2048] bf16 (LDS transpose) ----------------
__global__ __launch_bounds__(256) void prep_wt(const float* __restrict__ Wq,
                                               const float* __restrict__ Wk,
                                               const float* __restrict__ Wv,
                                               ushort* __restrict__ wt){
    __shared__ float ld[64][129];
    const int w  = blockIdx.y;
    const int k0 = blockIdx.x * 64;
    const int tid = threadIdx.x;
    const float* W = (w == 0) ? Wq : ((w == 1) ? Wk : Wv);
    #pragma unroll
    for (int ii = 0; ii < 32; ii++){
        int idx = tid + 256 * ii;
        int row = idx >> 7, col = idx & 127;
        ld[row][col] = W[(size_t)(k0 + row) * HEAD + col];
    }
    __syncthreads();
    int n  = tid >> 1;
    int kh = (tid & 1) * 32;
    __attribute__((aligned(16))) ushort tmp[32];
    #pragma unroll
    for (int ii = 0; ii < 32; ii++) tmp[ii] = f2bf(ld[kh + ii][n]);
    ushort* dst = wt + (size_t)(w * HEAD + n) * EMBED + k0 + kh;
    #pragma unroll
    for (int q = 0; q < 4; q++)
        *(short8*)(dst + q * 8) = *(const short8*)(tmp + q * 8);
}

// ---------------- Fused QKV GEMM: [16384 x 2048] x [2048 x 384], x read ONCE ----------------
// BM=64, BN=384, BK=64, 1024 thr = 16 waves (2m x 8n; wave tile 32x48). Grid 256 = 1 block/CU,
// but 4 waves/SIMD for latency hiding. W dbuf via GLL; x dbuf reg-staged. Issue-early/drain-late.
__global__ __launch_bounds__(1024) void qkv_gemm(const float* __restrict__ x,
                                                 const ushort* __restrict__ wt,
                                                 const float* __restrict__ bq,
                                                 const float* __restrict__ bk,
                                                 const float* __restrict__ bv,
                                                 ushort* __restrict__ Qb,
                                                 ushort* __restrict__ Kb,
                                                 ushort* __restrict__ Vt){
    __shared__ char smem[116736];
    // xsb(buf) = smem + buf*9216             [64][144B] padded bf16
    // wlb(buf) = smem + 18432 + buf*49152    [384][128B] linear, chunk-swizzled
    float* ts = (float*)smem;                  // epilogue V transpose [64][132] f32

    const int mtile = blockIdx.x;
    const int tid   = threadIdx.x;
    const int lane  = tid & 63;
    const int wid   = tid >> 6;                // 0..15
    const int l15   = lane & 15, lhi = lane >> 4;
    const int wm    = wid >> 3,  wn  = wid & 7;
    const int xrow0 = mtile * 64;

    const int srow = tid >> 4;      // 0..63 (x stage row)
    const int ssub = tid & 15;      // float4 index within row (k = ssub*4)

    const int grow = lane >> 3;     // gll: row within 8-row group
    const int gch  = lane & 7;      // gll: 16B chunk

    f32x4 acc[2][3];
    #pragma unroll
    for (int i = 0; i < 2; i++)
        #pragma unroll
        for (int j = 0; j < 3; j++) acc[i][j] = (f32x4){0.f,0.f,0.f,0.f};

    float4 xr;
    const int NK = EMBED / 64;

    // ---- prologue: stage kt=0 ----
    {
        xr = *(const float4*)(x + (size_t)(xrow0 + srow) * EMBED + ssub * 4);
        #pragma unroll
        for (int g = 0; g < 3; g++){
            int r0  = wid * 24 + g * 8;
            int row = r0 + grow;
            GLL16(wt + (size_t)row * EMBED + ((gch ^ grow) * 8), smem + 18432 + r0 * 128);
        }
        uint2 pk;
        pk.x = (unsigned)f2bf(xr.x) | ((unsigned)f2bf(xr.y) << 16);
        pk.y = (unsigned)f2bf(xr.z) | ((unsigned)f2bf(xr.w) << 16);
        *(uint2*)(smem + srow * 144 + ssub * 8) = pk;
    }
    __syncthreads();

    int cur = 0;
    for (int kt = 0; kt < NK; ++kt){
        char* xsb_c = smem + cur * 9216;
        char* wlb_c = smem + 18432 + cur * 49152;
        char* xsb_n = smem + (cur ^ 1) * 9216;
        char* wlb_n = smem + 18432 + (cur ^ 1) * 49152;
        // issue next-tile loads early (hidden under compute; drained at the barrier)
        if (kt < NK - 1){
            xr = *(const float4*)(x + (size_t)(xrow0 + srow) * EMBED + (kt + 1) * 64 + ssub * 4);
            const ushort* wsrc = wt + (kt + 1) * 64;
            #pragma unroll
            for (int g = 0; g < 3; g++){
                int r0  = wid * 24 + g * 8;
                int row = r0 + grow;
                GLL16(wsrc + (size_t)row * EMBED + ((gch ^ grow) * 8), wlb_n + r0 * 128);
            }
        }
        // compute from current buffer
        #pragma unroll
        for (int kc = 0; kc < 2; kc++){
            bf16x8 af[2], bfj[3];
            #pragma unroll
            for (int i = 0; i < 2; i++)
                af[i] = *(const bf16x8*)(xsb_c + (wm*32 + i*16 + l15) * 144 + kc*64 + lhi*16);
            #pragma unroll
            for (int j = 0; j < 3; j++){
                int row = wn*48 + j*16 + l15;
                bfj[j] = *(const bf16x8*)(wlb_c + row * 128 + (((kc*4 + lhi) ^ (l15 & 7)) * 16));
            }
            #pragma unroll
            for (int i = 0; i < 2; i++)
                #pragma unroll
                for (int j = 0; j < 3; j++)
                    acc[i][j] = MFMA16(af[i], bfj[j], acc[i][j]);
        }
        // write staged x into next buffer (auto-waits only the float4)
        if (kt < NK - 1){
            uint2 pk;
            pk.x = (unsigned)f2bf(xr.x) | ((unsigned)f2bf(xr.y) << 16);
            pk.y = (unsigned)f2bf(xr.z) | ((unsigned)f2bf(xr.w) << 16);
            *(uint2*)(xsb_n + srow * 144 + ssub * 8) = pk;
        }
        __syncthreads();
        cur ^= 1;
    }

    // ---- epilogue ----
    float bval[3];
    #pragma unroll
    for (int j = 0; j < 3; j++){
        int c = wn*48 + j*16 + l15;
        bval[j] = (c < 128) ? bq[c] : ((c < 256) ? bk[c - 128] : bv[c - 256]);
    }
    #pragma unroll
    for (int j = 0; j < 3; j++){
        int cb = wn*48 + j*16;          // 16-aligned; wholly within Q, K, or V
        if (cb < 256){
            ushort* dst = (cb < 128) ? Qb : Kb;
            int cl = (cb & 127) + l15;
            #pragma unroll
            for (int i = 0; i < 2; i++)
                #pragma unroll
                for (int r = 0; r < 4; r++){
                    int m = mtile*64 + wm*32 + i*16 + lhi*4 + r;
                    dst[(size_t)m * HEAD + cl] = f2bf(acc[i][j][r] + bval[j]);
                }
        }
    }
    __syncthreads();   // done with xsb/wlb; reuse as ts
    #pragma unroll
    for (int j = 0; j < 3; j++){
        int cb = wn*48 + j*16;
        if (cb >= 256){
            int vc = cb - 256 + l15;
            #pragma unroll
            for (int i = 0; i < 2; i++)
                #pragma unroll
                for (int r = 0; r < 4; r++){
                    int ml = wm*32 + i*16 + lhi*4 + r;
                    ts[ml * 132 + vc] = acc[i][j][r] + bval[j];
                }
        }
    }
    __syncthreads();
    {   // transpose out: V [64 rows][128 cols] -> Vt [8][128][2048]
        int n  = tid >> 3;              // 0..127 col
        int mc = (tid & 7) * 8;         // 8-row group
        int bb = mtile >> 5;
        int trow = (mtile & 31) * 64 + mc;
        __attribute__((aligned(16))) ushort tmp[8];
        #pragma unroll
        for (int ii = 0; ii < 8; ii++) tmp[ii] = f2bf(ts[(mc + ii) * 132 + n]);
        ushort* dst = Vt + ((size_t)(bb * HEAD + n)) * SEQ + trow;
        *(short8*)dst = *(const short8*)tmp;
    }
}

// ---------------- Flash attention, causal, kv-split x2, async-staged ----------------
__global__ __launch_bounds__(256) void attn(const ushort* __restrict__ Qb,
                                            const ushort* __restrict__ Kb,
                                            const ushort* __restrict__ Vt,
                                            float* __restrict__ po,
                                            float* __restrict__ pm,
                                            float* __restrict__ pl){
    __shared__ char smem[40960];
    char* Ks = smem;            // [64 kv][256 B] chunk-swizzled (^row&15)
    char* Vs = smem + 16384;    // [128 d][128 B] chunk-swizzled (^d&7)
    char* Ps = smem + 32768;    // 4 waves x [16 q][128 B] chunk-swizzled (^q&7)

    const int slot = blockIdx.x;
    const int b    = blockIdx.y;
    const int qi   = slot >> 1;
    const int qt   = (b < 4) ? qi : (31 - qi);     // anti-correlated pairing
    const int half = slot & 1;
    const int NT   = qt + 1;
    const int tmid = (NT + 1) >> 1;
    const int t0   = half ? tmid : 0;
    const int t1   = half ? NT : tmid;

    const int qb    = qt * 64;
    const int tid   = threadIdx.x;
    const int lane  = tid & 63, wid = tid >> 6;
    const int l15   = lane & 15, lhi = lane >> 4;
    const float scale = 0.08838834764831845f;   // 1/sqrt(128)

    bf16x8 qf[4];
    {
        const ushort* qp = Qb + ((size_t)(b * SEQ + qb + wid * 16 + l15)) * HEAD;
        #pragma unroll
        for (int kc = 0; kc < 4; kc++)
            qf[kc] = *(const bf16x8*)(qp + kc * 32 + lhi * 8);
    }

    f32x4 o[8];
    #pragma unroll
    for (int d = 0; d < 8; d++) o[d] = (f32x4){0.f,0.f,0.f,0.f};
    float mr[4] = {-1e30f,-1e30f,-1e30f,-1e30f};
    float lr[4] = {0.f,0.f,0.f,0.f};

    char* Pw = Ps + wid * 2048;

    const int krow = tid >> 4, kch = tid & 15;   // K stage coords
    const int vd   = tid >> 3, vch = tid & 7;    // V stage coords

    short8 kr[4], vr[4];
    {
        const int kvb = t0 * 64;
        #pragma unroll
        for (int j = 0; j < 4; j++)
            kr[j] = *(const short8*)(Kb + ((size_t)(b * SEQ + kvb + krow + 16*j)) * HEAD + kch * 8);
        #pragma unroll
        for (int j = 0; j < 4; j++)
            vr[j] = *(const short8*)(Vt + ((size_t)(b * HEAD + vd + 32*j)) * SEQ + kvb + vch * 8);
    }

    for (int t = t0; t < t1; ++t){
        __syncthreads();
        #pragma unroll
        for (int j = 0; j < 4; j++){
            int row = krow + 16*j;
            *(short8*)(Ks + row * 256 + ((kch ^ (row & 15)) * 16)) = kr[j];
        }
        #pragma unroll
        for (int j = 0; j < 4; j++){
            int d = vd + 32*j;
            *(short8*)(Vs + d * 128 + ((vch ^ (d & 7)) * 16)) = vr[j];
        }
        if (t + 1 < t1){
            const int kvb2 = (t + 1) * 64;
            #pragma unroll
            for (int j = 0; j < 4; j++)
                kr[j] = *(const short8*)(Kb + ((size_t)(b * SEQ + kvb2 + krow + 16*j)) * HEAD + kch * 8);
            #pragma unroll
            for (int j = 0; j < 4; j++)
                vr[j] = *(const short8*)(Vt + ((size_t)(b * HEAD + vd + 32*j)) * SEQ + kvb2 + vch * 8);
        }
        asm volatile("s_waitcnt lgkmcnt(0)" ::: "memory");
        __builtin_amdgcn_s_barrier();
        __builtin_amdgcn_sched_barrier(0);

        const int kvb = t * 64;
        f32x4 s[4];
        #pragma unroll
        for (int ns = 0; ns < 4; ns++){
            s[ns] = (f32x4){0.f,0.f,0.f,0.f};
            int row = ns * 16 + l15;
            #pragma unroll
            for (int kc = 0; kc < 4; kc++){
                int ch = (kc * 4 + lhi) ^ (row & 15);
                bf16x8 bfr = *(const bf16x8*)(Ks + row * 256 + ch * 16);
                s[ns] = MFMA16(qf[kc], bfr, s[ns]);
            }
        }

        float mx[4];
        #pragma unroll
        for (int r = 0; r < 4; r++){
            #pragma unroll
            for (int ns = 0; ns < 4; ns++){
                float v = s[ns][r] * scale;
                if (t == qt){
                    int kvg = kvb + ns * 16 + l15;
                    int qg  = qb + wid * 16 + lhi * 4 + r;
                    if (kvg > qg) v = -1e30f;
                }
                s[ns][r] = v;
            }
            float m0 = fmaxf(fmaxf(s[0][r], s[1][r]), fmaxf(s[2][r], s[3][r]));
            m0 = fmaxf(m0, __shfl_xor(m0, 1));
            m0 = fmaxf(m0, __shfl_xor(m0, 2));
            m0 = fmaxf(m0, __shfl_xor(m0, 4));
            m0 = fmaxf(m0, __shfl_xor(m0, 8));
            mx[r] = m0;
        }
        float alpha[4];
        #pragma unroll
        for (int r = 0; r < 4; r++){
            float mn = fmaxf(mr[r], mx[r]);
            alpha[r] = __expf(mr[r] - mn);
            mr[r] = mn;
            float sum = 0.f;
            #pragma unroll
            for (int ns = 0; ns < 4; ns++){
                float p = __expf(s[ns][r] - mn);
                s[ns][r] = p;
                sum += p;
            }
            sum += __shfl_xor(sum, 1);
            sum += __shfl_xor(sum, 2);
            sum += __shfl_xor(sum, 4);
            sum += __shfl_xor(sum, 8);
            lr[r] = lr[r] * alpha[r] + sum;
        }
        #pragma unroll
        for (int d = 0; d < 8; d++)
            #pragma unroll
            for (int r = 0; r < 4; r++) o[d][r] *= alpha[r];

        #pragma unroll
        for (int ns = 0; ns < 4; ns++)
            #pragma unroll
            for (int r = 0; r < 4; r++){
                int row = lhi * 4 + r;
                int byteoff = row * 128 + (((ns * 16 + l15) * 2) ^ ((row & 7) << 4));
                *(ushort*)(Pw + byteoff) = f2bf(s[ns][r]);
            }
        asm volatile("s_waitcnt lgkmcnt(0)" ::: "memory");
        __builtin_amdgcn_sched_barrier(0);

        #pragma unroll
        for (int kc = 0; kc < 2; kc++){
            int abyte = l15 * 128 + ((kc * 64 + lhi * 16) ^ ((l15 & 7) << 4));
            bf16x8 af = *(const bf16x8*)(Pw + abyte);
            #pragma unroll
            for (int ds = 0; ds < 8; ds++){
                int drow = ds * 16 + l15;
                int bbyte = drow * 128 + ((kc * 64 + lhi * 16) ^ ((drow & 7) << 4));
                bf16x8 bfr = *(const bf16x8*)(Vs + bbyte);
                o[ds] = MFMA16(af, bfr, o[ds]);
            }
        }
    }

    float* pob = po + ((size_t)half * 16384 + (size_t)b * SEQ) * HEAD;
    #pragma unroll
    for (int r = 0; r < 4; r++){
        int q = qb + wid * 16 + lhi * 4 + r;
        #pragma unroll
        for (int ds = 0; ds < 8; ds++)
            pob[(size_t)q * HEAD + ds * 16 + l15] = o[ds][r];
        if (l15 == 0){
            pm[half * 16384 + b * SEQ + q] = mr[r];
            pl[half * 16384 + b * SEQ + q] = lr[r];
        }
    }
}

// ---------------- merge two kv-halves ----------------
__global__ __launch_bounds__(256) void merge(const float* __restrict__ po,
                                             const float* __restrict__ pm,
                                             const float* __restrict__ pl,
                                             float* __restrict__ out){
    int g = blockIdx.x * 256 + threadIdx.x;
    int row = g >> 2;
    int dq  = (g & 3) * 32;
    float m0 = pm[row], m1 = pm[16384 + row];
    float l0 = pl[row], l1 = pl[16384 + row];
    float M  = fmaxf(m0, m1);
    float w0 = __expf(m0 - M), w1 = __expf(m1 - M);
    float inv = 1.0f / (w0 * l0 + w1 * l1);
    const float4* p0 = (const float4*)(po + (size_t)row * HEAD + dq);
    const float4* p1 = (const float4*)(po + (size_t)(16384 + row) * HEAD + dq);
    float4* op = (float4*)(out + (size_t)row * HEAD + dq);
    #pragma unroll
    for (int i = 0; i < 8; i++){
        float4 a = p0[i], c = p1[i];
        float4 r;
        r.x = (w0*a.x + w1*c.x) * inv;
        r.y = (w0*a.y + w1*c.y) * inv;
        r.z = (w0*a.z + w1*c.z) * inv;
        r.w = (w0*a.w + w1*c.w) * inv;
        op[i] = r;
    }
}

extern "C" void kernel_launch(void* const* d_in, const int* in_sizes, int n_in,
                              void* d_out, int out_size, void* d_ws, size_t ws_size,
                              hipStream_t stream){
    const float* x  = (const float*)d_in[0];
    const float* Wq = (const float*)d_in[1];
    const float* bq = (const float*)d_in[2];
    const float* Wk = (const float*)d_in[3];
    const float* bk = (const float*)d_in[4];
    const float* Wv = (const float*)d_in[5];
    const float* bv = (const float*)d_in[6];
    float* out = (float*)d_out;

    char* ws = (char*)d_ws;
    ushort* Qb = (ushort*)ws;                                  // 4 MB   [16384][128]
    ushort* Kb = (ushort*)(ws + (size_t)4  * 1024 * 1024);     // 4 MB   [16384][128]
    ushort* Vt = (ushort*)(ws + (size_t)8  * 1024 * 1024);     // 4 MB   [8][128][2048]
    ushort* Wt = (ushort*)(ws + (size_t)12 * 1024 * 1024);     // 1.57MB [384][2048]
    float*  po = (float*) (ws + (size_t)14 * 1024 * 1024);     // 16.8MB [2][16384][128]
    float*  pm = (float*) (ws + (size_t)31 * 1024 * 1024);     // 131KB  [2][16384]
    float*  pl = (float*) (ws + (size_t)31 * 1024 * 1024 + 262144);

    prep_wt <<<dim3(32, 3), 256, 0, stream>>>(Wq, Wk, Wv, Wt);
    qkv_gemm<<<dim3(256), 1024, 0, stream>>>(x, Wt, bq, bk, bv, Qb, Kb, Vt);
    attn    <<<dim3(64, 8), 256, 0, stream>>>(Qb, Kb, Vt, po, pm, pl);
    merge   <<<256, 256, 0, stream>>>(po, pm, pl, out);
}